// Round 13
// baseline (222.966 us; speedup 1.0000x reference)
//
#include <hip/hip_runtime.h>

#define N_NODES 200000
#define N_EDGES 6400000
#define N_GRAPHS 1024
#define F_IN 16
#define H1 8
#define H2 16
#define STEPS 4

#define NB 1024          // node buckets
#define BNODES 196       // nodes per bucket
#define NSLAB 8          // per-XCD sub-slabs per bucket
#define CAPS 1024        // capacity per (bucket, slab); mean 784, sd 28 -> 8.6 sigma
#define BSLOTS (NSLAB * CAPS)   // 8192 slots per bucket
#define CAP 8784         // padded lsrc LDS capacity
#define SMAX 320         // set2set LDS staging capacity
#define RPT 16           // BSLOTS / 512
#define RPADD 200        // rowptr stride per bucket
#define ZIDX N_NODES     // index of the all-zero feature row (padding target)

typedef _Float16 half8 __attribute__((ext_vector_type(8)));
typedef int int4v __attribute__((ext_vector_type(4)));

// ---------------- y1 = x @ W1l.T fp16; also writes zero rows at ZIDX -------------
__global__ void k_y1(const float* __restrict__ x, const float* __restrict__ W1l,
                     _Float16* __restrict__ y1, _Float16* __restrict__ h1) {
    int n = blockIdx.x * blockDim.x + threadIdx.x;
    if (n > N_NODES) return;
    if (n == N_NODES) {
        half8 z = {};
        *(half8*)&y1[(long long)ZIDX * H1] = z;
        *(half8*)&h1[(long long)ZIDX * H1] = z;
        return;
    }
    float xv[F_IN];
#pragma unroll
    for (int k = 0; k < F_IN; k++) xv[k] = x[(long long)n * F_IN + k];
    half8 o;
#pragma unroll
    for (int j = 0; j < H1; j++) {
        float s = 0.f;
#pragma unroll
        for (int k = 0; k < F_IN; k++) s += W1l[j * F_IN + k] * xv[k];
        o[j] = (_Float16)s;
    }
    *(half8*)&y1[(long long)n * H1] = o;
}

// ---------------- compact edges into XCD-private bucket slabs --------------------
#define FILL_T 16384   // 1024 thr x 16
__global__ __launch_bounds__(1024) void k_bin_fill(const int* __restrict__ src,
                                                   const int* __restrict__ dst,
                                                   int* __restrict__ gcur8,
                                                   unsigned int* __restrict__ grec) {
    __shared__ int scnt[NB];
    __shared__ int soff[NB];
    int tid = threadIdx.x;
    int slab = blockIdx.x & (NSLAB - 1);
    long long ebase = (long long)blockIdx.x * FILL_T;
    scnt[tid] = 0;
    __syncthreads();
    unsigned int rec[16];
    unsigned int meta[16];
#pragma unroll
    for (int u = 0; u < 16; u++) {
        long long e = ebase + (long long)u * 1024 + tid;
        if (e < N_EDGES) {
            int d = __builtin_nontemporal_load(dst + e);
            int s = __builtin_nontemporal_load(src + e);
            int b = d / BNODES;
            int dl = d - b * BNODES;
            rec[u] = ((unsigned int)s << 8) | (unsigned int)dl;
            int r = atomicAdd(&scnt[b], 1);
            meta[u] = ((unsigned int)b << 16) | (unsigned int)r;
        } else {
            meta[u] = 0xFFFFFFFFu;
        }
    }
    __syncthreads();
    {
        int c = scnt[tid];
        soff[tid] = c ? atomicAdd(&gcur8[tid * NSLAB + slab], c) : 0;
    }
    __syncthreads();
#pragma unroll
    for (int u = 0; u < 16; u++) {
        if (meta[u] != 0xFFFFFFFFu) {
            int b = meta[u] >> 16;
            unsigned int slot = (unsigned int)soff[b] + (meta[u] & 0xFFFFu);
            if (slot < CAPS)
                grec[(size_t)b * BSLOTS + slab * CAPS + slot] = rec[u];
        }
    }
}

// ---------------- conv1: padded counting sort, wave-coop gather, export ----------
__global__ __launch_bounds__(512) void k_conv1(
    const float* __restrict__ x, const _Float16* __restrict__ y1,
    const int* __restrict__ gcur8, unsigned int* __restrict__ grec,
    int* __restrict__ growptr,
    const float* __restrict__ b1l, const float* __restrict__ W1r,
    _Float16* __restrict__ h1) {
    __shared__ __align__(16) int lsrc[CAP];
    __shared__ int hist[BNODES];
    __shared__ int start[BNODES + 1];
    __shared__ int slen[BNODES];
    __shared__ int wsum[8];
    __shared__ int cnt8[NSLAB];
    int b = blockIdx.x, tid = threadIdx.x;
    size_t base = (size_t)b * BSLOTS;
    if (tid < NSLAB) {
        int c = gcur8[b * NSLAB + tid];
        cnt8[tid] = c > CAPS ? CAPS : c;
    }
    for (int j = tid; j < BNODES; j += 512) hist[j] = 0;
    __syncthreads();
    unsigned int rec[RPT];
#pragma unroll
    for (int u = 0; u < RPT; u++) {
        int idx = u * 512 + tid;
        int s = idx >> 10, slot = idx & (CAPS - 1);
        if (slot < cnt8[s]) {
            rec[u] = __builtin_nontemporal_load(grec + base + idx);
            atomicAdd(&hist[rec[u] & 255], 1);
        } else {
            rec[u] = 0xFFFFFFFFu;
        }
    }
    __syncthreads();
    // padded exclusive scan: plen = ceil4(len)
    {
        int v = (tid < BNODES) ? hist[tid] : 0;
        int pl = (v + 3) & ~3;
        int lane = tid & 63, w = tid >> 6;
        int s = pl;
#pragma unroll
        for (int off = 1; off < 64; off <<= 1) {
            int u = __shfl_up(s, off);
            if (lane >= off) s += u;
        }
        if (lane == 63) wsum[w] = s;
        __syncthreads();
        int bb = 0;
        for (int i = 0; i < w; i++) bb += wsum[i];
        s += bb;
        int ps = s - pl;
        if (tid < BNODES) {
            start[tid] = ps; slen[tid] = v;
            growptr[b * RPADD + tid] = (ps << 16) | v;
        }
        if (tid == BNODES) {
            start[tid] = ps;
            growptr[b * RPADD + tid] = (ps << 16);
        }
    }
    __syncthreads();
    int ptotal = start[BNODES];
    for (int j = tid; j < BNODES; j += 512) hist[j] = 0;      // reuse as cursor
    for (int j = tid; j < ptotal; j += 512) lsrc[j] = ZIDX;   // pre-fill pads
    __syncthreads();
#pragma unroll
    for (int u = 0; u < RPT; u++) {
        if (rec[u] != 0xFFFFFFFFu) {
            int dl = rec[u] & 255;
            int k = atomicAdd(&hist[dl], 1);
            lsrc[start[dl] + k] = (int)(rec[u] >> 8);
        }
    }
    __syncthreads();
    // export padded sorted list (aligned int4, nontemporal)
    {
        int pe = ptotal > BSLOTS ? BSLOTS : ptotal;
        for (int j = tid * 4; j < pe; j += 2048) {
            int4v vv = *(const int4v*)&lsrc[j];
            __builtin_nontemporal_store(vv, (int4v*)(grec + base + j));
        }
    }
    // wave-cooperative gather: 16 groups of 32 lanes, one node per group
    int gid = tid >> 5, l = tid & 31;
    for (int dl = gid; dl < BNODES; dl += 16) {
        int n = b * BNODES + dl;
        int ps0 = start[dl], pe = start[dl + 1];
        float acc[H1];
#pragma unroll
        for (int k = 0; k < H1; k++) acc[k] = 0.f;
        for (int e = ps0 + l; e < pe; e += 32) {
            half8 v = *(const half8*)&y1[(long long)lsrc[e] * H1];
#pragma unroll
            for (int k = 0; k < H1; k++) acc[k] += (float)v[k];
        }
#pragma unroll
        for (int off = 16; off; off >>= 1) {
#pragma unroll
            for (int k = 0; k < H1; k++) acc[k] += __shfl_xor(acc[k], off);
        }
        if (l < H1 && n < N_NODES) {
            float aj = acc[0];
#pragma unroll
            for (int k = 1; k < H1; k++) if (l == k) aj = acc[k];
            float inv = 1.0f / fmaxf((float)slen[dl], 1.0f);
            float s = aj * inv + b1l[l];
#pragma unroll
            for (int k = 0; k < F_IN; k++) s += W1r[l * F_IN + k] * x[(long long)n * F_IN + k];
            h1[(long long)n * H1 + l] = (_Float16)fmaxf(s, 0.0f);
        }
    }
}

// ---------------- conv2: node-parallel, 32 lanes per node ------------------------
__global__ __launch_bounds__(256) void k_conv2(
    const _Float16* __restrict__ h1,
    const unsigned int* __restrict__ gsorted, const int* __restrict__ growptr,
    const float* __restrict__ b2l, const float* __restrict__ W2l,
    const float* __restrict__ W2r, float* __restrict__ h2) {
    int tid = threadIdx.x;
    int gid = tid >> 5, l = tid & 31;
    int n = blockIdx.x * 8 + gid;
    if (n >= N_NODES) return;
    int b = n / BNODES, dl = n - b * BNODES;
    int pack0 = growptr[b * RPADD + dl];
    int pack1 = growptr[b * RPADD + dl + 1];
    int ps0 = pack0 >> 16, sl = pack0 & 0xFFFF;
    int pe = pack1 >> 16;
    const unsigned int* seg = gsorted + (size_t)b * BSLOTS;
    float acc[H1];
#pragma unroll
    for (int k = 0; k < H1; k++) acc[k] = 0.f;
    for (int e = ps0 + l; e < pe; e += 32) {
        int idx = (int)__builtin_nontemporal_load(seg + e);   // coalesced
        half8 v = *(const half8*)&h1[(long long)idx * H1];
#pragma unroll
        for (int k = 0; k < H1; k++) acc[k] += (float)v[k];
    }
#pragma unroll
    for (int off = 16; off; off >>= 1) {
#pragma unroll
        for (int k = 0; k < H1; k++) acc[k] += __shfl_xor(acc[k], off);
    }
    if (l < H2) {
        float inv = 1.0f / fmaxf((float)sl, 1.0f);
        half8 hr = *(const half8*)&h1[(long long)n * H1];   // broadcast row
        float s = b2l[l];
#pragma unroll
        for (int k = 0; k < H1; k++)
            s += W2l[l * H1 + k] * (acc[k] * inv) + W2r[l * H1 + k] * (float)hr[k];
        h2[(long long)n * H2 + l] = fmaxf(s, 0.0f);
    }
}

// ---------------- graph segment pointers from sorted batch -----------------------
__global__ void k_ptr(const int* __restrict__ batch, int* __restrict__ ptr) {
    int n = blockIdx.x * blockDim.x + threadIdx.x;
    if (n >= N_NODES) return;
    int b = batch[n];
    int bp = (n == 0) ? -1 : batch[n - 1];
    for (int g = bp + 1; g <= b; g++) ptr[g] = n;
    if (n == N_NODES - 1) {
        for (int g = b + 1; g <= N_GRAPHS; g++) ptr[g] = N_NODES;
    }
}

// ---------------- Set2Set + final FC: one block per graph, h2 staged in LDS ------
__global__ __launch_bounds__(256) void k_set2set(
    const float* __restrict__ h2, const int* __restrict__ ptr,
    const float* __restrict__ Wih, const float* __restrict__ Whh,
    const float* __restrict__ bih, const float* __restrict__ bhh,
    const float* __restrict__ Wfc, const float* __restrict__ bfc,
    float* __restrict__ out) {
    int b = blockIdx.x;
    int start = ptr[b], end = ptr[b + 1], cnt = end - start;
    __shared__ float sx[SMAX][H2 + 1];
    __shared__ float el[SMAX];
    __shared__ float sh[H2], sc[H2], sq[2 * H2], sg[4 * H2];
    __shared__ float red[4][17];
    __shared__ float s_emax, s_asum, s_r[H2];
    int tid = threadIdx.x;
    int wid = tid >> 6, lane = tid & 63;
    bool fit = (cnt <= SMAX);

    if (fit) {
        for (int i = start + tid; i < end; i += 256) {
            const float4* p = (const float4*)&h2[(long long)i * H2];
            float4 r0 = p[0], r1 = p[1], r2 = p[2], r3 = p[3];
            float* row = sx[i - start];
            row[0] = r0.x; row[1] = r0.y; row[2] = r0.z; row[3] = r0.w;
            row[4] = r1.x; row[5] = r1.y; row[6] = r1.z; row[7] = r1.w;
            row[8] = r2.x; row[9] = r2.y; row[10] = r2.z; row[11] = r2.w;
            row[12] = r3.x; row[13] = r3.y; row[14] = r3.z; row[15] = r3.w;
        }
    }
    if (tid < H2) { sh[tid] = 0.f; sc[tid] = 0.f; }
    if (tid < 2 * H2) sq[tid] = 0.f;
    __syncthreads();

    for (int step = 0; step < STEPS; step++) {
        if (tid < 64) {
            float g = bih[tid] + bhh[tid];
#pragma unroll
            for (int k = 0; k < 2 * H2; k++) g += Wih[tid * (2 * H2) + k] * sq[k];
#pragma unroll
            for (int k = 0; k < H2; k++) g += Whh[tid * H2 + k] * sh[k];
            sg[tid] = g;
        }
        __syncthreads();
        if (tid < H2) {
            float ig = 1.f / (1.f + expf(-sg[tid]));
            float fg = 1.f / (1.f + expf(-sg[H2 + tid]));
            float gg = tanhf(sg[2 * H2 + tid]);
            float og = 1.f / (1.f + expf(-sg[3 * H2 + tid]));
            float cc = fg * sc[tid] + ig * gg;
            sc[tid] = cc;
            sh[tid] = og * tanhf(cc);
        }
        __syncthreads();

        float lmax = -3.0e38f;
        if (fit) {
            for (int ii = tid; ii < cnt; ii += 256) {
                float e = 0.f;
#pragma unroll
                for (int k = 0; k < H2; k++) e += sx[ii][k] * sh[k];
                el[ii] = e;
                lmax = fmaxf(lmax, e);
            }
        } else {
            for (int i = start + tid; i < end; i += 256) {
                float e = 0.f;
#pragma unroll
                for (int k = 0; k < H2; k++) e += h2[(long long)i * H2 + k] * sh[k];
                lmax = fmaxf(lmax, e);
            }
        }
        for (int off = 32; off; off >>= 1) lmax = fmaxf(lmax, __shfl_down(lmax, off));
        if (lane == 0) red[wid][0] = lmax;
        __syncthreads();
        if (tid == 0) {
            float m = red[0][0];
            for (int w = 1; w < 4; w++) m = fmaxf(m, red[w][0]);
            s_emax = m;
        }
        __syncthreads();
        float emax = s_emax;

        float asum = 0.f, rloc[H2];
#pragma unroll
        for (int k = 0; k < H2; k++) rloc[k] = 0.f;
        if (fit) {
            for (int ii = tid; ii < cnt; ii += 256) {
                float a = expf(el[ii] - emax);
                asum += a;
#pragma unroll
                for (int k = 0; k < H2; k++) rloc[k] += a * sx[ii][k];
            }
        } else {
            for (int i = start + tid; i < end; i += 256) {
                float hv[H2];
                float e = 0.f;
#pragma unroll
                for (int k = 0; k < H2; k++) { hv[k] = h2[(long long)i * H2 + k]; e += hv[k] * sh[k]; }
                float a = expf(e - emax);
                asum += a;
#pragma unroll
                for (int k = 0; k < H2; k++) rloc[k] += a * hv[k];
            }
        }
        for (int off = 32; off; off >>= 1) {
            asum += __shfl_down(asum, off);
#pragma unroll
            for (int k = 0; k < H2; k++) rloc[k] += __shfl_down(rloc[k], off);
        }
        if (lane == 0) {
            red[wid][16] = asum;
#pragma unroll
            for (int k = 0; k < H2; k++) red[wid][k] = rloc[k];
        }
        __syncthreads();
        if (tid < 17) {
            float s = red[0][tid] + red[1][tid] + red[2][tid] + red[3][tid];
            if (tid == 16) s_asum = s; else s_r[tid] = s;
        }
        __syncthreads();
        if (tid < H2) {
            float rr = (cnt > 0 && s_asum > 0.f) ? s_r[tid] / s_asum : 0.0f;
            sq[tid] = sh[tid];
            sq[H2 + tid] = rr;
        }
        __syncthreads();
    }

    if (tid < 2) {
        float s = bfc[tid];
#pragma unroll
        for (int k = 0; k < 2 * H2; k++) s += Wfc[tid * (2 * H2) + k] * sq[k];
        out[b * 2 + tid] = s;
    }
}

extern "C" void kernel_launch(void* const* d_in, const int* in_sizes, int n_in,
                              void* d_out, int out_size, void* d_ws, size_t ws_size,
                              hipStream_t stream) {
    const float* x   = (const float*)d_in[0];
    const int*   ei  = (const int*)d_in[1];
    const int*   src = ei;
    const int*   dst = ei + N_EDGES;
    const int*   batch = (const int*)d_in[2];
    const float* W1l = (const float*)d_in[3];
    const float* b1l = (const float*)d_in[4];
    const float* W1r = (const float*)d_in[5];
    const float* W2l = (const float*)d_in[6];
    const float* b2l = (const float*)d_in[7];
    const float* W2r = (const float*)d_in[8];
    const float* Wih = (const float*)d_in[9];
    const float* Whh = (const float*)d_in[10];
    const float* bih = (const float*)d_in[11];
    const float* bhh = (const float*)d_in[12];
    const float* Wfc = (const float*)d_in[13];
    const float* bfc = (const float*)d_in[14];
    float* out = (float*)d_out;

    // workspace layout (all offsets 16B-aligned)
    char* ws = (char*)d_ws;
    unsigned int* grec = (unsigned int*)ws;                 // NB*BSLOTS (33.5 MB); becomes gsorted
    int* gcur8 = (int*)(grec + (size_t)NB * BSLOTS);        // NB*NSLAB (32 KB)
    int* growptr = gcur8 + NB * NSLAB;                      // NB*RPADD (~0.8 MB)
    _Float16* y1 = (_Float16*)(growptr + (size_t)NB * RPADD); // (N_NODES+4)*H1 fp16
    _Float16* h1 = y1 + (size_t)(N_NODES + 4) * H1;         // (N_NODES+4)*H1 fp16
    float* h2  = (float*)(h1 + (size_t)(N_NODES + 4) * H1); // N_NODES*H2 fp32
    int*   ptr = (int*)(h2 + (size_t)N_NODES * H2);         // N_GRAPHS+4

    hipMemsetAsync(gcur8, 0, (size_t)NB * NSLAB * sizeof(int), stream);

    int nb_node1 = (N_NODES + 1 + 255) / 256;
    int nb_node = (N_NODES + 255) / 256;
    int nb_fill = (int)(((long long)N_EDGES + FILL_T - 1) / FILL_T);
    int nb_conv2 = (N_NODES + 7) / 8;

    k_y1<<<nb_node1, 256, 0, stream>>>(x, W1l, y1, h1);
    k_bin_fill<<<nb_fill, 1024, 0, stream>>>(src, dst, gcur8, grec);
    k_conv1<<<NB, 512, 0, stream>>>(x, y1, gcur8, grec, growptr, b1l, W1r, h1);
    k_conv2<<<nb_conv2, 256, 0, stream>>>(h1, grec, growptr, b2l, W2l, W2r, h2);
    k_ptr<<<nb_node, 256, 0, stream>>>(batch, ptr);
    k_set2set<<<N_GRAPHS, 256, 0, stream>>>(h2, ptr, Wih, Whh, bih, bhh, Wfc, bfc, out);
}

// Round 14
// 194.138 us; speedup vs baseline: 1.1485x; 1.1485x over previous
//
#include <hip/hip_runtime.h>

#define N_NODES 200000
#define N_EDGES 6400000
#define N_GRAPHS 1024
#define F_IN 16
#define H1 8
#define H2 16
#define STEPS 4

#define NB 1024          // node buckets
#define BNODES 196       // nodes per bucket
#define NSLAB 8          // per-XCD sub-slabs per bucket
#define CAPS 1024        // capacity per (bucket, slab); mean 784, sd 28 -> 8.6 sigma
#define BSLOTS (NSLAB * CAPS)   // 8192 slots per bucket
#define CAP 8784         // padded lsrc LDS capacity
#define SMAX 320         // set2set LDS staging capacity
#define RPT 16           // BSLOTS / 512
#define RPADD 200        // rowptr stride per bucket
#define ZIDX N_NODES     // index of the all-zero feature row (padding target)

typedef _Float16 half8 __attribute__((ext_vector_type(8)));
typedef int int4v __attribute__((ext_vector_type(4)));

// ---- prep: y1 = x @ W1l.T fp16 (+zero pad rows), graph ptr, gcur8 zero ----------
__global__ void k_prep(const float* __restrict__ x, const float* __restrict__ W1l,
                       const int* __restrict__ batch,
                       _Float16* __restrict__ y1, _Float16* __restrict__ h1,
                       int* __restrict__ ptr, int* __restrict__ gcur8) {
    int n = blockIdx.x * blockDim.x + threadIdx.x;
    if (n < NB * NSLAB) gcur8[n] = 0;
    if (n > N_NODES) return;
    if (n == N_NODES) {
        half8 z = {};
        *(half8*)&y1[(long long)ZIDX * H1] = z;
        *(half8*)&h1[(long long)ZIDX * H1] = z;
        return;
    }
    // graph segment pointers from sorted batch
    {
        int b = batch[n];
        int bp = (n == 0) ? -1 : batch[n - 1];
        for (int g = bp + 1; g <= b; g++) ptr[g] = n;
        if (n == N_NODES - 1) {
            for (int g = b + 1; g <= N_GRAPHS; g++) ptr[g] = N_NODES;
        }
    }
    float xv[F_IN];
#pragma unroll
    for (int k = 0; k < F_IN; k++) xv[k] = x[(long long)n * F_IN + k];
    half8 o;
#pragma unroll
    for (int j = 0; j < H1; j++) {
        float s = 0.f;
#pragma unroll
        for (int k = 0; k < F_IN; k++) s += W1l[j * F_IN + k] * xv[k];
        o[j] = (_Float16)s;
    }
    *(half8*)&y1[(long long)n * H1] = o;
}

// ---------------- compact edges into XCD-private bucket slabs --------------------
// record = (src << 8) | dst_local; slab lane = blockIdx & 7 (XCD under round-robin)
#define FILL_T 16384   // 1024 thr x 16
__global__ __launch_bounds__(1024) void k_bin_fill(const int* __restrict__ src,
                                                   const int* __restrict__ dst,
                                                   int* __restrict__ gcur8,
                                                   unsigned int* __restrict__ grec) {
    __shared__ int scnt[NB];
    __shared__ int soff[NB];
    int tid = threadIdx.x;
    int slab = blockIdx.x & (NSLAB - 1);
    long long ebase = (long long)blockIdx.x * FILL_T;
    scnt[tid] = 0;
    __syncthreads();
    unsigned int rec[16];
    unsigned int meta[16];
#pragma unroll
    for (int u = 0; u < 16; u++) {
        long long e = ebase + (long long)u * 1024 + tid;
        if (e < N_EDGES) {
            int d = __builtin_nontemporal_load(dst + e);
            int s = __builtin_nontemporal_load(src + e);
            int b = d / BNODES;
            int dl = d - b * BNODES;
            rec[u] = ((unsigned int)s << 8) | (unsigned int)dl;
            int r = atomicAdd(&scnt[b], 1);
            meta[u] = ((unsigned int)b << 16) | (unsigned int)r;
        } else {
            meta[u] = 0xFFFFFFFFu;
        }
    }
    __syncthreads();
    {
        int c = scnt[tid];
        soff[tid] = c ? atomicAdd(&gcur8[tid * NSLAB + slab], c) : 0;
    }
    __syncthreads();
#pragma unroll
    for (int u = 0; u < 16; u++) {
        if (meta[u] != 0xFFFFFFFFu) {
            int b = meta[u] >> 16;
            unsigned int slot = (unsigned int)soff[b] + (meta[u] & 0xFFFFu);
            if (slot < CAPS)
                grec[(size_t)b * BSLOTS + slab * CAPS + slot] = rec[u];
        }
    }
}

// ---------------- conv1: padded counting sort, int4 gather, export ---------------
__global__ __launch_bounds__(512) void k_conv1(
    const float* __restrict__ x, const _Float16* __restrict__ y1,
    const int* __restrict__ gcur8, unsigned int* __restrict__ grec,
    int* __restrict__ growptr,
    const float* __restrict__ b1l, const float* __restrict__ W1r,
    _Float16* __restrict__ h1) {
    __shared__ __align__(16) int lsrc[CAP];
    __shared__ int hist[BNODES];
    __shared__ int start[BNODES + 1];
    __shared__ int slen[BNODES];
    __shared__ int wsum[8];
    __shared__ int cnt8[NSLAB];
    int b = blockIdx.x, tid = threadIdx.x;
    size_t base = (size_t)b * BSLOTS;
    if (tid < NSLAB) {
        int c = gcur8[b * NSLAB + tid];
        cnt8[tid] = c > CAPS ? CAPS : c;
    }
    for (int j = tid; j < BNODES; j += 512) hist[j] = 0;
    __syncthreads();
    unsigned int rec[RPT];
#pragma unroll
    for (int u = 0; u < RPT; u++) {
        int idx = u * 512 + tid;           // idx < 8192
        int s = idx >> 10, slot = idx & (CAPS - 1);
        if (slot < cnt8[s]) {
            rec[u] = __builtin_nontemporal_load(grec + base + idx);
            atomicAdd(&hist[rec[u] & 255], 1);
        } else {
            rec[u] = 0xFFFFFFFFu;
        }
    }
    __syncthreads();
    // padded exclusive scan: plen = ceil4(len); start = padded offsets
    {
        int v = (tid < BNODES) ? hist[tid] : 0;
        int pl = (v + 3) & ~3;
        int lane = tid & 63, w = tid >> 6;
        int s = pl;
#pragma unroll
        for (int off = 1; off < 64; off <<= 1) {
            int u = __shfl_up(s, off);
            if (lane >= off) s += u;
        }
        if (lane == 63) wsum[w] = s;
        __syncthreads();
        int bb = 0;
        for (int i = 0; i < w; i++) bb += wsum[i];
        s += bb;
        int ps = s - pl;
        if (tid < BNODES) {
            start[tid] = ps; slen[tid] = v;
            growptr[b * RPADD + tid] = (ps << 16) | v;
        }
        if (tid == BNODES) {
            start[tid] = ps;
            growptr[b * RPADD + tid] = (ps << 16);
        }
    }
    __syncthreads();
    int ptotal = start[BNODES];
    for (int j = tid; j < BNODES; j += 512) hist[j] = 0;      // reuse as cursor
    for (int j = tid; j < ptotal; j += 512) lsrc[j] = ZIDX;   // pre-fill pads
    __syncthreads();
#pragma unroll
    for (int u = 0; u < RPT; u++) {
        if (rec[u] != 0xFFFFFFFFu) {
            int dl = rec[u] & 255;
            int k = atomicAdd(&hist[dl], 1);
            lsrc[start[dl] + k] = (int)(rec[u] >> 8);
        }
    }
    __syncthreads();
    // export padded sorted list (aligned int4, nontemporal)
    {
        int pe = ptotal > BSLOTS ? BSLOTS : ptotal;
        for (int j = tid * 4; j < pe; j += 2048) {
            int4v vv = *(const int4v*)&lsrc[j];
            __builtin_nontemporal_store(vv, (int4v*)(grec + base + j));
        }
    }
    // pair-gather: 2 threads per node, int4 blocks from LDS
    if (tid < 2 * BNODES) {
        int dl = tid >> 1, half = tid & 1;
        int n = b * BNODES + dl;
        int ps0 = start[dl];
        int nblk = (start[dl + 1] - ps0) >> 2;
        int c0 = half ? (nblk >> 1) : 0;
        int c1 = half ? nblk : (nblk >> 1);
        float acc[H1];
#pragma unroll
        for (int k = 0; k < H1; k++) acc[k] = 0.f;
        for (int blk = c0; blk < c1; blk++) {
            int4v a = *(const int4v*)&lsrc[ps0 + 4 * blk];
            half8 v0 = *(const half8*)&y1[(long long)a.x * H1];
            half8 v1 = *(const half8*)&y1[(long long)a.y * H1];
            half8 v2 = *(const half8*)&y1[(long long)a.z * H1];
            half8 v3 = *(const half8*)&y1[(long long)a.w * H1];
#pragma unroll
            for (int k = 0; k < H1; k++)
                acc[k] += ((float)v0[k] + (float)v1[k]) + ((float)v2[k] + (float)v3[k]);
        }
#pragma unroll
        for (int k = 0; k < H1; k++) acc[k] += __shfl_xor(acc[k], 1);
        if (half == 0 && n < N_NODES) {
            float inv = 1.0f / fmaxf((float)slen[dl], 1.0f);
            float xv[F_IN];
#pragma unroll
            for (int k = 0; k < F_IN; k++) xv[k] = x[(long long)n * F_IN + k];
            half8 o;
#pragma unroll
            for (int j = 0; j < H1; j++) {
                float s = acc[j] * inv + b1l[j];
#pragma unroll
                for (int k = 0; k < F_IN; k++) s += W1r[j * F_IN + k] * xv[k];
                o[j] = (_Float16)fmaxf(s, 0.0f);
            }
            *(half8*)&h1[(long long)n * H1] = o;
        }
    }
}

// ---------------- conv2: pure gather via padded CSR, int4 index loads ------------
__global__ __launch_bounds__(512) void k_conv2(
    const _Float16* __restrict__ h1,
    const unsigned int* __restrict__ gsorted, const int* __restrict__ growptr,
    const float* __restrict__ b2l, const float* __restrict__ W2l,
    const float* __restrict__ W2r, float* __restrict__ h2) {
    int b = blockIdx.x, tid = threadIdx.x;
    if (tid >= 2 * BNODES) return;
    int dl = tid >> 1, half = tid & 1;
    int n = b * BNODES + dl;
    if (n >= N_NODES) return;   // pair-consistent: both threads of pair exit
    int pack0 = growptr[b * RPADD + dl];
    int pack1 = growptr[b * RPADD + dl + 1];
    int ps0 = pack0 >> 16, sl = pack0 & 0xFFFF;
    int nblk = ((pack1 >> 16) - ps0) >> 2;
    const int4v* seg4 = (const int4v*)(gsorted + (size_t)b * BSLOTS + ps0);
    int c0 = half ? (nblk >> 1) : 0;
    int c1 = half ? nblk : (nblk >> 1);
    float acc[H1];
#pragma unroll
    for (int k = 0; k < H1; k++) acc[k] = 0.f;
    for (int blk = c0; blk < c1; blk++) {
        int4v a = __builtin_nontemporal_load(seg4 + blk);
        half8 v0 = *(const half8*)&h1[(long long)a.x * H1];
        half8 v1 = *(const half8*)&h1[(long long)a.y * H1];
        half8 v2 = *(const half8*)&h1[(long long)a.z * H1];
        half8 v3 = *(const half8*)&h1[(long long)a.w * H1];
#pragma unroll
        for (int k = 0; k < H1; k++)
            acc[k] += ((float)v0[k] + (float)v1[k]) + ((float)v2[k] + (float)v3[k]);
    }
#pragma unroll
    for (int k = 0; k < H1; k++) acc[k] += __shfl_xor(acc[k], 1);
    if (half == 0) {
        float inv = 1.0f / fmaxf((float)sl, 1.0f);
        float av[H1], hv[H1];
        half8 hr = *(const half8*)&h1[(long long)n * H1];
#pragma unroll
        for (int k = 0; k < H1; k++) { hv[k] = (float)hr[k]; av[k] = acc[k] * inv; }
        float o[H2];
#pragma unroll
        for (int j = 0; j < H2; j++) {
            float s = b2l[j];
#pragma unroll
            for (int k = 0; k < H1; k++) s += W2l[j * H1 + k] * av[k] + W2r[j * H1 + k] * hv[k];
            o[j] = fmaxf(s, 0.0f);
        }
        *(float4*)&h2[(long long)n * H2] = make_float4(o[0], o[1], o[2], o[3]);
        *(float4*)&h2[(long long)n * H2 + 4] = make_float4(o[4], o[5], o[6], o[7]);
        *(float4*)&h2[(long long)n * H2 + 8] = make_float4(o[8], o[9], o[10], o[11]);
        *(float4*)&h2[(long long)n * H2 + 12] = make_float4(o[12], o[13], o[14], o[15]);
    }
}

// ---------------- Set2Set + final FC: one block per graph, h2 staged in LDS ------
__global__ __launch_bounds__(256) void k_set2set(
    const float* __restrict__ h2, const int* __restrict__ ptr,
    const float* __restrict__ Wih, const float* __restrict__ Whh,
    const float* __restrict__ bih, const float* __restrict__ bhh,
    const float* __restrict__ Wfc, const float* __restrict__ bfc,
    float* __restrict__ out) {
    int b = blockIdx.x;
    int start = ptr[b], end = ptr[b + 1], cnt = end - start;
    __shared__ float sx[SMAX][H2 + 1];
    __shared__ float el[SMAX];
    __shared__ float sh[H2], sc[H2], sq[2 * H2], sg[4 * H2];
    __shared__ float red[4][17];
    __shared__ float s_emax, s_asum, s_r[H2];
    int tid = threadIdx.x;
    int wid = tid >> 6, lane = tid & 63;
    bool fit = (cnt <= SMAX);

    if (fit) {
        for (int i = start + tid; i < end; i += 256) {
            const float4* p = (const float4*)&h2[(long long)i * H2];
            float4 r0 = p[0], r1 = p[1], r2 = p[2], r3 = p[3];
            float* row = sx[i - start];
            row[0] = r0.x; row[1] = r0.y; row[2] = r0.z; row[3] = r0.w;
            row[4] = r1.x; row[5] = r1.y; row[6] = r1.z; row[7] = r1.w;
            row[8] = r2.x; row[9] = r2.y; row[10] = r2.z; row[11] = r2.w;
            row[12] = r3.x; row[13] = r3.y; row[14] = r3.z; row[15] = r3.w;
        }
    }
    if (tid < H2) { sh[tid] = 0.f; sc[tid] = 0.f; }
    if (tid < 2 * H2) sq[tid] = 0.f;
    __syncthreads();

    for (int step = 0; step < STEPS; step++) {
        if (tid < 64) {
            float g = bih[tid] + bhh[tid];
#pragma unroll
            for (int k = 0; k < 2 * H2; k++) g += Wih[tid * (2 * H2) + k] * sq[k];
#pragma unroll
            for (int k = 0; k < H2; k++) g += Whh[tid * H2 + k] * sh[k];
            sg[tid] = g;
        }
        __syncthreads();
        if (tid < H2) {
            float ig = 1.f / (1.f + expf(-sg[tid]));
            float fg = 1.f / (1.f + expf(-sg[H2 + tid]));
            float gg = tanhf(sg[2 * H2 + tid]);
            float og = 1.f / (1.f + expf(-sg[3 * H2 + tid]));
            float cc = fg * sc[tid] + ig * gg;
            sc[tid] = cc;
            sh[tid] = og * tanhf(cc);
        }
        __syncthreads();

        float lmax = -3.0e38f;
        if (fit) {
            for (int ii = tid; ii < cnt; ii += 256) {
                float e = 0.f;
#pragma unroll
                for (int k = 0; k < H2; k++) e += sx[ii][k] * sh[k];
                el[ii] = e;
                lmax = fmaxf(lmax, e);
            }
        } else {
            for (int i = start + tid; i < end; i += 256) {
                float e = 0.f;
#pragma unroll
                for (int k = 0; k < H2; k++) e += h2[(long long)i * H2 + k] * sh[k];
                lmax = fmaxf(lmax, e);
            }
        }
        for (int off = 32; off; off >>= 1) lmax = fmaxf(lmax, __shfl_down(lmax, off));
        if (lane == 0) red[wid][0] = lmax;
        __syncthreads();
        if (tid == 0) {
            float m = red[0][0];
            for (int w = 1; w < 4; w++) m = fmaxf(m, red[w][0]);
            s_emax = m;
        }
        __syncthreads();
        float emax = s_emax;

        float asum = 0.f, rloc[H2];
#pragma unroll
        for (int k = 0; k < H2; k++) rloc[k] = 0.f;
        if (fit) {
            for (int ii = tid; ii < cnt; ii += 256) {
                float a = expf(el[ii] - emax);
                asum += a;
#pragma unroll
                for (int k = 0; k < H2; k++) rloc[k] += a * sx[ii][k];
            }
        } else {
            for (int i = start + tid; i < end; i += 256) {
                float hv[H2];
                float e = 0.f;
#pragma unroll
                for (int k = 0; k < H2; k++) { hv[k] = h2[(long long)i * H2 + k]; e += hv[k] * sh[k]; }
                float a = expf(e - emax);
                asum += a;
#pragma unroll
                for (int k = 0; k < H2; k++) rloc[k] += a * hv[k];
            }
        }
        for (int off = 32; off; off >>= 1) {
            asum += __shfl_down(asum, off);
#pragma unroll
            for (int k = 0; k < H2; k++) rloc[k] += __shfl_down(rloc[k], off);
        }
        if (lane == 0) {
            red[wid][16] = asum;
#pragma unroll
            for (int k = 0; k < H2; k++) red[wid][k] = rloc[k];
        }
        __syncthreads();
        if (tid < 17) {
            float s = red[0][tid] + red[1][tid] + red[2][tid] + red[3][tid];
            if (tid == 16) s_asum = s; else s_r[tid] = s;
        }
        __syncthreads();
        if (tid < H2) {
            float rr = (cnt > 0 && s_asum > 0.f) ? s_r[tid] / s_asum : 0.0f;
            sq[tid] = sh[tid];
            sq[H2 + tid] = rr;
        }
        __syncthreads();
    }

    if (tid < 2) {
        float s = bfc[tid];
#pragma unroll
        for (int k = 0; k < 2 * H2; k++) s += Wfc[tid * (2 * H2) + k] * sq[k];
        out[b * 2 + tid] = s;
    }
}

extern "C" void kernel_launch(void* const* d_in, const int* in_sizes, int n_in,
                              void* d_out, int out_size, void* d_ws, size_t ws_size,
                              hipStream_t stream) {
    const float* x   = (const float*)d_in[0];
    const int*   ei  = (const int*)d_in[1];
    const int*   src = ei;
    const int*   dst = ei + N_EDGES;
    const int*   batch = (const int*)d_in[2];
    const float* W1l = (const float*)d_in[3];
    const float* b1l = (const float*)d_in[4];
    const float* W1r = (const float*)d_in[5];
    const float* W2l = (const float*)d_in[6];
    const float* b2l = (const float*)d_in[7];
    const float* W2r = (const float*)d_in[8];
    const float* Wih = (const float*)d_in[9];
    const float* Whh = (const float*)d_in[10];
    const float* bih = (const float*)d_in[11];
    const float* bhh = (const float*)d_in[12];
    const float* Wfc = (const float*)d_in[13];
    const float* bfc = (const float*)d_in[14];
    float* out = (float*)d_out;

    // workspace layout (all offsets 16B-aligned)
    char* ws = (char*)d_ws;
    unsigned int* grec = (unsigned int*)ws;                 // NB*BSLOTS (33.5 MB); becomes gsorted
    int* gcur8 = (int*)(grec + (size_t)NB * BSLOTS);        // NB*NSLAB (32 KB)
    int* growptr = gcur8 + NB * NSLAB;                      // NB*RPADD (~0.8 MB)
    _Float16* y1 = (_Float16*)(growptr + (size_t)NB * RPADD); // (N_NODES+4)*H1 fp16
    _Float16* h1 = y1 + (size_t)(N_NODES + 4) * H1;         // (N_NODES+4)*H1 fp16
    float* h2  = (float*)(h1 + (size_t)(N_NODES + 4) * H1); // N_NODES*H2 fp32
    int*   ptr = (int*)(h2 + (size_t)N_NODES * H2);         // N_GRAPHS+4

    int nb_prep = (N_NODES + 1 + 255) / 256;
    int nb_fill = (int)(((long long)N_EDGES + FILL_T - 1) / FILL_T);

    k_prep<<<nb_prep, 256, 0, stream>>>(x, W1l, batch, y1, h1, ptr, gcur8);
    k_bin_fill<<<nb_fill, 1024, 0, stream>>>(src, dst, gcur8, grec);
    k_conv1<<<NB, 512, 0, stream>>>(x, y1, gcur8, grec, growptr, b1l, W1r, h1);
    k_conv2<<<NB, 512, 0, stream>>>(h1, grec, growptr, b2l, W2l, W2r, h2);
    k_set2set<<<N_GRAPHS, 256, 0, stream>>>(h2, ptr, Wih, Whh, bih, bhh, Wfc, bfc, out);
}

// Round 15
// 181.824 us; speedup vs baseline: 1.2263x; 1.0677x over previous
//
#include <hip/hip_runtime.h>

#define N_NODES 200000
#define N_EDGES 6400000
#define N_GRAPHS 1024
#define F_IN 16
#define H1 8
#define H2 16
#define STEPS 4

#define NB 1024          // node buckets
#define BNODES 196       // nodes per bucket
#define NSLAB 8          // per-XCD sub-slabs per bucket
#define CAPS 1024        // capacity per (bucket, slab); mean 784, sd 28 -> 8.6 sigma
#define BSLOTS (NSLAB * CAPS)   // 8192 slots per bucket
#define CAP 8784         // padded lsrc LDS capacity
#define SMAX 320         // set2set LDS staging capacity
#define RPT 16           // BSLOTS / 512
#define RPADD 200        // rowptr stride per bucket
#define ZIDX N_NODES     // index of the all-zero feature row (padding target)

typedef _Float16 half8 __attribute__((ext_vector_type(8)));
typedef int int4v __attribute__((ext_vector_type(4)));

// ---- prep: y1 = x @ W1l.T fp16 (+zero pad rows), graph ptr, gcur8 zero ----------
__global__ void k_prep(const float* __restrict__ x, const float* __restrict__ W1l,
                       const int* __restrict__ batch,
                       _Float16* __restrict__ y1, _Float16* __restrict__ h1,
                       int* __restrict__ ptr, int* __restrict__ gcur8) {
    int n = blockIdx.x * blockDim.x + threadIdx.x;
    if (n < NB * NSLAB) gcur8[n] = 0;
    if (n > N_NODES) return;
    if (n == N_NODES) {
        half8 z = {};
        *(half8*)&y1[(long long)ZIDX * H1] = z;
        *(half8*)&h1[(long long)ZIDX * H1] = z;
        return;
    }
    {
        int b = batch[n];
        int bp = (n == 0) ? -1 : batch[n - 1];
        for (int g = bp + 1; g <= b; g++) ptr[g] = n;
        if (n == N_NODES - 1) {
            for (int g = b + 1; g <= N_GRAPHS; g++) ptr[g] = N_NODES;
        }
    }
    float xv[F_IN];
#pragma unroll
    for (int k = 0; k < F_IN; k++) xv[k] = x[(long long)n * F_IN + k];
    half8 o;
#pragma unroll
    for (int j = 0; j < H1; j++) {
        float s = 0.f;
#pragma unroll
        for (int k = 0; k < F_IN; k++) s += W1l[j * F_IN + k] * xv[k];
        o[j] = (_Float16)s;
    }
    *(half8*)&y1[(long long)n * H1] = o;
}

// ---------------- compact edges into XCD-private bucket slabs --------------------
// record = (src << 8) | dst_local; slab lane = blockIdx & 7 (XCD under round-robin)
#define FILL_T 16384   // 1024 thr x 16
__global__ __launch_bounds__(1024) void k_bin_fill(const int* __restrict__ src,
                                                   const int* __restrict__ dst,
                                                   int* __restrict__ gcur8,
                                                   unsigned int* __restrict__ grec) {
    __shared__ int scnt[NB];
    __shared__ int soff[NB];
    int tid = threadIdx.x;
    int slab = blockIdx.x & (NSLAB - 1);
    long long ebase = (long long)blockIdx.x * FILL_T;
    scnt[tid] = 0;
    __syncthreads();
    unsigned int rec[16];
    unsigned int meta[16];
#pragma unroll
    for (int u = 0; u < 16; u++) {
        long long e = ebase + (long long)u * 1024 + tid;
        if (e < N_EDGES) {
            int d = __builtin_nontemporal_load(dst + e);
            int s = __builtin_nontemporal_load(src + e);
            int b = d / BNODES;
            int dl = d - b * BNODES;
            rec[u] = ((unsigned int)s << 8) | (unsigned int)dl;
            int r = atomicAdd(&scnt[b], 1);
            meta[u] = ((unsigned int)b << 16) | (unsigned int)r;
        } else {
            meta[u] = 0xFFFFFFFFu;
        }
    }
    __syncthreads();
    {
        int c = scnt[tid];
        soff[tid] = c ? atomicAdd(&gcur8[tid * NSLAB + slab], c) : 0;
    }
    __syncthreads();
#pragma unroll
    for (int u = 0; u < 16; u++) {
        if (meta[u] != 0xFFFFFFFFu) {
            int b = meta[u] >> 16;
            unsigned int slot = (unsigned int)soff[b] + (meta[u] & 0xFFFFu);
            if (slot < CAPS)
                grec[(size_t)b * BSLOTS + slab * CAPS + slot] = rec[u];
        }
    }
}

// ---------------- conv1: padded counting sort, int4 gather, export ---------------
__global__ __launch_bounds__(512) void k_conv1(
    const float* __restrict__ x, const _Float16* __restrict__ y1,
    const int* __restrict__ gcur8, unsigned int* __restrict__ grec,
    int* __restrict__ growptr,
    const float* __restrict__ b1l, const float* __restrict__ W1r,
    _Float16* __restrict__ h1) {
    __shared__ __align__(16) int lsrc[CAP];
    __shared__ int hist[BNODES];
    __shared__ int start[BNODES + 1];
    __shared__ int slen[BNODES];
    __shared__ int wsum[8];
    __shared__ int cnt8[NSLAB];
    int b = blockIdx.x, tid = threadIdx.x;
    size_t base = (size_t)b * BSLOTS;
    if (tid < NSLAB) {
        int c = gcur8[b * NSLAB + tid];
        cnt8[tid] = c > CAPS ? CAPS : c;
    }
    for (int j = tid; j < BNODES; j += 512) hist[j] = 0;
    __syncthreads();
    unsigned int rec[RPT];
#pragma unroll
    for (int u = 0; u < RPT; u++) {
        int idx = u * 512 + tid;           // idx < 8192
        int s = idx >> 10, slot = idx & (CAPS - 1);
        if (slot < cnt8[s]) {
            rec[u] = __builtin_nontemporal_load(grec + base + idx);
            atomicAdd(&hist[rec[u] & 255], 1);
        } else {
            rec[u] = 0xFFFFFFFFu;
        }
    }
    __syncthreads();
    // padded exclusive scan: plen = ceil4(len); start = padded offsets
    {
        int v = (tid < BNODES) ? hist[tid] : 0;
        int pl = (v + 3) & ~3;
        int lane = tid & 63, w = tid >> 6;
        int s = pl;
#pragma unroll
        for (int off = 1; off < 64; off <<= 1) {
            int u = __shfl_up(s, off);
            if (lane >= off) s += u;
        }
        if (lane == 63) wsum[w] = s;
        __syncthreads();
        int bb = 0;
        for (int i = 0; i < w; i++) bb += wsum[i];
        s += bb;
        int ps = s - pl;
        if (tid < BNODES) {
            start[tid] = ps; slen[tid] = v;
            growptr[b * RPADD + tid] = (ps << 16) | v;
        }
        if (tid == BNODES) {
            start[tid] = ps;
            growptr[b * RPADD + tid] = (ps << 16);
        }
    }
    __syncthreads();
    int ptotal = start[BNODES];
    for (int j = tid; j < BNODES; j += 512) hist[j] = 0;      // reuse as cursor
    for (int j = tid; j < ptotal; j += 512) lsrc[j] = ZIDX;   // pre-fill pads
    __syncthreads();
#pragma unroll
    for (int u = 0; u < RPT; u++) {
        if (rec[u] != 0xFFFFFFFFu) {
            int dl = rec[u] & 255;
            int k = atomicAdd(&hist[dl], 1);
            lsrc[start[dl] + k] = (int)(rec[u] >> 8);
        }
    }
    __syncthreads();
    // export padded sorted list (aligned int4, nontemporal)
    {
        int pe = ptotal > BSLOTS ? BSLOTS : ptotal;
        for (int j = tid * 4; j < pe; j += 2048) {
            int4v vv = *(const int4v*)&lsrc[j];
            __builtin_nontemporal_store(vv, (int4v*)(grec + base + j));
        }
    }
    // pair-gather: 2 threads per node, int4 blocks from LDS
    if (tid < 2 * BNODES) {
        int dl = tid >> 1, half = tid & 1;
        int n = b * BNODES + dl;
        int ps0 = start[dl];
        int nblk = (start[dl + 1] - ps0) >> 2;
        int c0 = half ? (nblk >> 1) : 0;
        int c1 = half ? nblk : (nblk >> 1);
        float acc[H1];
#pragma unroll
        for (int k = 0; k < H1; k++) acc[k] = 0.f;
        for (int blk = c0; blk < c1; blk++) {
            int4v a = *(const int4v*)&lsrc[ps0 + 4 * blk];
            half8 v0 = *(const half8*)&y1[(long long)a.x * H1];
            half8 v1 = *(const half8*)&y1[(long long)a.y * H1];
            half8 v2 = *(const half8*)&y1[(long long)a.z * H1];
            half8 v3 = *(const half8*)&y1[(long long)a.w * H1];
#pragma unroll
            for (int k = 0; k < H1; k++)
                acc[k] += ((float)v0[k] + (float)v1[k]) + ((float)v2[k] + (float)v3[k]);
        }
#pragma unroll
        for (int k = 0; k < H1; k++) acc[k] += __shfl_xor(acc[k], 1);
        if (half == 0 && n < N_NODES) {
            float inv = 1.0f / fmaxf((float)slen[dl], 1.0f);
            float xv[F_IN];
#pragma unroll
            for (int k = 0; k < F_IN; k++) xv[k] = x[(long long)n * F_IN + k];
            half8 o;
#pragma unroll
            for (int j = 0; j < H1; j++) {
                float s = acc[j] * inv + b1l[j];
#pragma unroll
                for (int k = 0; k < F_IN; k++) s += W1r[j * F_IN + k] * xv[k];
                o[j] = (_Float16)fmaxf(s, 0.0f);
            }
            *(half8*)&h1[(long long)n * H1] = o;
        }
    }
}

// ---------------- conv2: CSR staged in LDS, pure scattered gathers ---------------
__global__ __launch_bounds__(448) void k_conv2(
    const _Float16* __restrict__ h1,
    const unsigned int* __restrict__ gsorted, const int* __restrict__ growptr,
    const float* __restrict__ b2l, const float* __restrict__ W2l,
    const float* __restrict__ W2r, float* __restrict__ h2) {
    __shared__ __align__(16) int lsrc[CAP];
    int b = blockIdx.x, tid = threadIdx.x;
    size_t base = (size_t)b * BSLOTS;
    int ptotal = growptr[b * RPADD + BNODES] >> 16;
    if (ptotal > BSLOTS) ptotal = BSLOTS;
    // stage the block's padded CSR segment into LDS (coalesced int4)
    int nb4 = (ptotal + 3) >> 2;
    for (int j = tid; j < nb4; j += 448) {
        int4v v = *(const int4v*)(gsorted + base + 4 * j);
        *(int4v*)&lsrc[4 * j] = v;
    }
    __syncthreads();
    if (tid >= 2 * BNODES) return;
    int dl = tid >> 1, half = tid & 1;
    int n = b * BNODES + dl;
    if (n >= N_NODES) return;   // pair-consistent: both threads of pair exit
    int pack0 = growptr[b * RPADD + dl];
    int pack1 = growptr[b * RPADD + dl + 1];
    int ps0 = pack0 >> 16, sl = pack0 & 0xFFFF;
    int nblk = ((pack1 >> 16) - ps0) >> 2;
    int c0 = half ? (nblk >> 1) : 0;
    int c1 = half ? nblk : (nblk >> 1);
    float acc[H1];
#pragma unroll
    for (int k = 0; k < H1; k++) acc[k] = 0.f;
    for (int blk = c0; blk < c1; blk++) {
        int4v a = *(const int4v*)&lsrc[ps0 + 4 * blk];
        half8 v0 = *(const half8*)&h1[(long long)a.x * H1];
        half8 v1 = *(const half8*)&h1[(long long)a.y * H1];
        half8 v2 = *(const half8*)&h1[(long long)a.z * H1];
        half8 v3 = *(const half8*)&h1[(long long)a.w * H1];
#pragma unroll
        for (int k = 0; k < H1; k++)
            acc[k] += ((float)v0[k] + (float)v1[k]) + ((float)v2[k] + (float)v3[k]);
    }
#pragma unroll
    for (int k = 0; k < H1; k++) acc[k] += __shfl_xor(acc[k], 1);
    if (half == 0) {
        float inv = 1.0f / fmaxf((float)sl, 1.0f);
        float av[H1], hv[H1];
        half8 hr = *(const half8*)&h1[(long long)n * H1];
#pragma unroll
        for (int k = 0; k < H1; k++) { hv[k] = (float)hr[k]; av[k] = acc[k] * inv; }
        float o[H2];
#pragma unroll
        for (int j = 0; j < H2; j++) {
            float s = b2l[j];
#pragma unroll
            for (int k = 0; k < H1; k++) s += W2l[j * H1 + k] * av[k] + W2r[j * H1 + k] * hv[k];
            o[j] = fmaxf(s, 0.0f);
        }
        *(float4*)&h2[(long long)n * H2] = make_float4(o[0], o[1], o[2], o[3]);
        *(float4*)&h2[(long long)n * H2 + 4] = make_float4(o[4], o[5], o[6], o[7]);
        *(float4*)&h2[(long long)n * H2 + 8] = make_float4(o[8], o[9], o[10], o[11]);
        *(float4*)&h2[(long long)n * H2 + 12] = make_float4(o[12], o[13], o[14], o[15]);
    }
}

// ---------------- Set2Set + final FC: one block per graph, h2 staged in LDS ------
__global__ __launch_bounds__(256) void k_set2set(
    const float* __restrict__ h2, const int* __restrict__ ptr,
    const float* __restrict__ Wih, const float* __restrict__ Whh,
    const float* __restrict__ bih, const float* __restrict__ bhh,
    const float* __restrict__ Wfc, const float* __restrict__ bfc,
    float* __restrict__ out) {
    int b = blockIdx.x;
    int start = ptr[b], end = ptr[b + 1], cnt = end - start;
    __shared__ float sx[SMAX][H2 + 1];
    __shared__ float el[SMAX];
    __shared__ float sh[H2], sc[H2], sq[2 * H2], sg[4 * H2];
    __shared__ float red[4][17];
    __shared__ float s_emax, s_asum, s_r[H2];
    int tid = threadIdx.x;
    int wid = tid >> 6, lane = tid & 63;
    bool fit = (cnt <= SMAX);

    if (fit) {
        for (int i = start + tid; i < end; i += 256) {
            const float4* p = (const float4*)&h2[(long long)i * H2];
            float4 r0 = p[0], r1 = p[1], r2 = p[2], r3 = p[3];
            float* row = sx[i - start];
            row[0] = r0.x; row[1] = r0.y; row[2] = r0.z; row[3] = r0.w;
            row[4] = r1.x; row[5] = r1.y; row[6] = r1.z; row[7] = r1.w;
            row[8] = r2.x; row[9] = r2.y; row[10] = r2.z; row[11] = r2.w;
            row[12] = r3.x; row[13] = r3.y; row[14] = r3.z; row[15] = r3.w;
        }
    }
    if (tid < H2) { sh[tid] = 0.f; sc[tid] = 0.f; }
    if (tid < 2 * H2) sq[tid] = 0.f;
    __syncthreads();

    for (int step = 0; step < STEPS; step++) {
        if (tid < 64) {
            float g = bih[tid] + bhh[tid];
#pragma unroll
            for (int k = 0; k < 2 * H2; k++) g += Wih[tid * (2 * H2) + k] * sq[k];
#pragma unroll
            for (int k = 0; k < H2; k++) g += Whh[tid * H2 + k] * sh[k];
            sg[tid] = g;
        }
        __syncthreads();
        if (tid < H2) {
            float ig = 1.f / (1.f + expf(-sg[tid]));
            float fg = 1.f / (1.f + expf(-sg[H2 + tid]));
            float gg = tanhf(sg[2 * H2 + tid]);
            float og = 1.f / (1.f + expf(-sg[3 * H2 + tid]));
            float cc = fg * sc[tid] + ig * gg;
            sc[tid] = cc;
            sh[tid] = og * tanhf(cc);
        }
        __syncthreads();

        float lmax = -3.0e38f;
        if (fit) {
            for (int ii = tid; ii < cnt; ii += 256) {
                float e = 0.f;
#pragma unroll
                for (int k = 0; k < H2; k++) e += sx[ii][k] * sh[k];
                el[ii] = e;
                lmax = fmaxf(lmax, e);
            }
        } else {
            for (int i = start + tid; i < end; i += 256) {
                float e = 0.f;
#pragma unroll
                for (int k = 0; k < H2; k++) e += h2[(long long)i * H2 + k] * sh[k];
                lmax = fmaxf(lmax, e);
            }
        }
        for (int off = 32; off; off >>= 1) lmax = fmaxf(lmax, __shfl_down(lmax, off));
        if (lane == 0) red[wid][0] = lmax;
        __syncthreads();
        if (tid == 0) {
            float m = red[0][0];
            for (int w = 1; w < 4; w++) m = fmaxf(m, red[w][0]);
            s_emax = m;
        }
        __syncthreads();
        float emax = s_emax;

        float asum = 0.f, rloc[H2];
#pragma unroll
        for (int k = 0; k < H2; k++) rloc[k] = 0.f;
        if (fit) {
            for (int ii = tid; ii < cnt; ii += 256) {
                float a = expf(el[ii] - emax);
                asum += a;
#pragma unroll
                for (int k = 0; k < H2; k++) rloc[k] += a * sx[ii][k];
            }
        } else {
            for (int i = start + tid; i < end; i += 256) {
                float hv[H2];
                float e = 0.f;
#pragma unroll
                for (int k = 0; k < H2; k++) { hv[k] = h2[(long long)i * H2 + k]; e += hv[k] * sh[k]; }
                float a = expf(e - emax);
                asum += a;
#pragma unroll
                for (int k = 0; k < H2; k++) rloc[k] += a * hv[k];
            }
        }
        for (int off = 32; off; off >>= 1) {
            asum += __shfl_down(asum, off);
#pragma unroll
            for (int k = 0; k < H2; k++) rloc[k] += __shfl_down(rloc[k], off);
        }
        if (lane == 0) {
            red[wid][16] = asum;
#pragma unroll
            for (int k = 0; k < H2; k++) red[wid][k] = rloc[k];
        }
        __syncthreads();
        if (tid < 17) {
            float s = red[0][tid] + red[1][tid] + red[2][tid] + red[3][tid];
            if (tid == 16) s_asum = s; else s_r[tid] = s;
        }
        __syncthreads();
        if (tid < H2) {
            float rr = (cnt > 0 && s_asum > 0.f) ? s_r[tid] / s_asum : 0.0f;
            sq[tid] = sh[tid];
            sq[H2 + tid] = rr;
        }
        __syncthreads();
    }

    if (tid < 2) {
        float s = bfc[tid];
#pragma unroll
        for (int k = 0; k < 2 * H2; k++) s += Wfc[tid * (2 * H2) + k] * sq[k];
        out[b * 2 + tid] = s;
    }
}

extern "C" void kernel_launch(void* const* d_in, const int* in_sizes, int n_in,
                              void* d_out, int out_size, void* d_ws, size_t ws_size,
                              hipStream_t stream) {
    const float* x   = (const float*)d_in[0];
    const int*   ei  = (const int*)d_in[1];
    const int*   src = ei;
    const int*   dst = ei + N_EDGES;
    const int*   batch = (const int*)d_in[2];
    const float* W1l = (const float*)d_in[3];
    const float* b1l = (const float*)d_in[4];
    const float* W1r = (const float*)d_in[5];
    const float* W2l = (const float*)d_in[6];
    const float* b2l = (const float*)d_in[7];
    const float* W2r = (const float*)d_in[8];
    const float* Wih = (const float*)d_in[9];
    const float* Whh = (const float*)d_in[10];
    const float* bih = (const float*)d_in[11];
    const float* bhh = (const float*)d_in[12];
    const float* Wfc = (const float*)d_in[13];
    const float* bfc = (const float*)d_in[14];
    float* out = (float*)d_out;

    // workspace layout (all offsets 16B-aligned)
    char* ws = (char*)d_ws;
    unsigned int* grec = (unsigned int*)ws;                 // NB*BSLOTS (33.5 MB); becomes gsorted
    int* gcur8 = (int*)(grec + (size_t)NB * BSLOTS);        // NB*NSLAB (32 KB)
    int* growptr = gcur8 + NB * NSLAB;                      // NB*RPADD (~0.8 MB)
    _Float16* y1 = (_Float16*)(growptr + (size_t)NB * RPADD); // (N_NODES+4)*H1 fp16
    _Float16* h1 = y1 + (size_t)(N_NODES + 4) * H1;         // (N_NODES+4)*H1 fp16
    float* h2  = (float*)(h1 + (size_t)(N_NODES + 4) * H1); // N_NODES*H2 fp32
    int*   ptr = (int*)(h2 + (size_t)N_NODES * H2);         // N_GRAPHS+4

    int nb_prep = (N_NODES + 1 + 255) / 256;
    int nb_fill = (int)(((long long)N_EDGES + FILL_T - 1) / FILL_T);

    k_prep<<<nb_prep, 256, 0, stream>>>(x, W1l, batch, y1, h1, ptr, gcur8);
    k_bin_fill<<<nb_fill, 1024, 0, stream>>>(src, dst, gcur8, grec);
    k_conv1<<<NB, 512, 0, stream>>>(x, y1, gcur8, grec, growptr, b1l, W1r, h1);
    k_conv2<<<NB, 448, 0, stream>>>(h1, grec, growptr, b2l, W2l, W2r, h2);
    k_set2set<<<N_GRAPHS, 256, 0, stream>>>(h2, ptr, Wih, Whh, bih, bhh, Wfc, bfc, out);
}